// Round 4
// baseline (524.646 us; speedup 1.0000x reference)
//
#include <hip/hip_runtime.h>

// MoE fp32: route top-2 -> gather -> bf16 MFMA GEMMs.
// v4: m97-style GEMMs (linear LDS, global_load_lds dwordx4 staging, 128x128
// tile, 16 MFMA/iter). Weights pre-transposed to bf16 (n,k) by wconv passes
// that are grid-FUSED into independent launches (wconv1 with xconv/router,
// wconv2 with gemm1) so they stream off the critical path. gemm2 keeps
// split-K=4 + fused atomic combine.

typedef __bf16 bf16;
typedef __bf16 bf16x8 __attribute__((ext_vector_type(8)));
typedef float floatx4 __attribute__((ext_vector_type(4)));

#define T_TOK 1024
#define HID 1024
#define FFN 4096
#define NEXP 8
#define BM 128
#define BN 128
#define BK 32

// global_load_lds: LDS dest = wave-uniform base + lane*16 (linear, no pad).
#define GLOAD16(g, l) __builtin_amdgcn_global_load_lds( \
    (const __attribute__((address_space(1))) void*)(g), \
    (__attribute__((address_space(3))) void*)(l), 16, 0, 0)

// ---------------- device bodies ----------------
__device__ __forceinline__ void wconv_body(const float* __restrict__ w,
                                           bf16* __restrict__ wt, int bid, int tid,
                                           int K, int N, int lgN, int lgKC) {
  int gid = bid * 256 + tid;
  int n = gid & (N - 1);
  int kc = (gid >> lgN) & ((K >> 5) - 1);
  int e = gid >> (lgN + lgKC);
  const float* src = w + ((size_t)e * K + (size_t)kc * 32) * N + n;
  bf16* dst = wt + ((size_t)e * N + n) * (size_t)K + kc * 32;
  float v[32];
#pragma unroll
  for (int j = 0; j < 32; j++) v[j] = src[(size_t)j * N];
  bf16x8 pk[4];
#pragma unroll
  for (int q = 0; q < 4; q++)
#pragma unroll
    for (int i = 0; i < 8; i++) pk[q][i] = (bf16)v[q * 8 + i];
#pragma unroll
  for (int q = 0; q < 4; q++) *(bf16x8*)(dst + q * 8) = pk[q];
}

__device__ __forceinline__ void xconv_body(const float* __restrict__ x,
                                           bf16* __restrict__ xb, int bid, int tid) {
  int i = bid * 256 + tid;
  float4 a = ((const float4*)x)[i * 2];
  float4 b = ((const float4*)x)[i * 2 + 1];
  bf16 t[8] = {(bf16)a.x, (bf16)a.y, (bf16)a.z, (bf16)a.w,
               (bf16)b.x, (bf16)b.y, (bf16)b.z, (bf16)b.w};
  *(bf16x8*)&xb[(size_t)i * 8] = *(bf16x8*)t;
}

__device__ __forceinline__ void router_body(const float* __restrict__ x,
                                            const float* __restrict__ gw,
                                            const float* __restrict__ gb,
                                            int* __restrict__ cnt, int* __restrict__ elist,
                                            float* __restrict__ ewt, int bid, int tid) {
  int wave = tid >> 6;
  int lane = tid & 63;
  int t = bid * 4 + wave;
  const float* xr = x + (size_t)t * HID;
  float xv[16];
#pragma unroll
  for (int j = 0; j < 16; j++) xv[j] = xr[lane + 64 * j];
  float logits[NEXP];
#pragma unroll
  for (int e = 0; e < NEXP; e++) {
    const float* g = gw + (size_t)e * HID;
    float s = 0.f;
#pragma unroll
    for (int j = 0; j < 16; j++) s += xv[j] * g[lane + 64 * j];
#pragma unroll
    for (int off = 32; off; off >>= 1) s += __shfl_xor(s, off, 64);
    logits[e] = s + gb[e];
  }
  int i0 = 0; float l0 = logits[0];
#pragma unroll
  for (int e = 1; e < NEXP; e++) if (logits[e] > l0) { l0 = logits[e]; i0 = e; }
  int i1 = -1; float l1 = -3.0e38f;
#pragma unroll
  for (int e = 0; e < NEXP; e++) if (e != i0 && logits[e] > l1) { l1 = logits[e]; i1 = e; }
  if (lane == 0) {
    float w0 = 1.f / (1.f + expf(l1 - l0));
    float w1 = 1.f - w0;
    int p0 = atomicAdd(cnt + i0, 1);
    elist[i0 * T_TOK + p0] = t * 2 + 0; ewt[i0 * T_TOK + p0] = w0;
    int p1 = atomicAdd(cnt + i1, 1);
    elist[i1 * T_TOK + p1] = t * 2 + 1; ewt[i1 * T_TOK + p1] = w1;
  }
}

// ---------------- Launch B: wconv1 | xconv | router (all independent) ----------------
__global__ __launch_bounds__(256)
void fusedB_k(const float* __restrict__ x, bf16* __restrict__ xb,
              const float* __restrict__ gw, const float* __restrict__ gb,
              int* __restrict__ cnt, int* __restrict__ elist, float* __restrict__ ewt,
              const float* __restrict__ w1, bf16* __restrict__ w1t) {
  int bid = blockIdx.x;
  int tid = threadIdx.x;
  if (bid < 4096) { wconv_body(w1, w1t, bid, tid, HID, FFN, 12, 5); return; }
  bid -= 4096;
  if (bid < 512) { xconv_body(x, xb, bid, tid); return; }
  router_body(x, gw, gb, cnt, elist, ewt, bid - 512, tid);
}

// ---------------- standalone wconv (serial fallback for w2) ----------------
__global__ __launch_bounds__(256)
void wconv_k(const float* __restrict__ w, bf16* __restrict__ wt,
             int K, int N, int lgN, int lgKC) {
  wconv_body(w, wt, blockIdx.x, threadIdx.x, K, N, lgN, lgKC);
}

// ---------------- Launch C: wconv2 | gemm1 (h = gelu(Xg @ w1 + b1)) ----------------
__global__ __launch_bounds__(256)
void gemm1f_k(int nconv, const float* __restrict__ w2, bf16* __restrict__ w2t,
              const bf16* __restrict__ xb, const bf16* __restrict__ w1t,
              const float* __restrict__ b1, const int* __restrict__ cnt,
              const int* __restrict__ elist, bf16* __restrict__ hbuf) {
  int tid = threadIdx.x;
  int bid = blockIdx.x;
  if (bid < nconv) { wconv_body(w2, w2t, bid, tid, FFN, HID, 10, 7); return; }
  int g = bid - nconv;
  int e = g >> 8;
  int m0 = ((g >> 5) & 7) * BM;
  int n0 = (g & 31) * BN;
  int c = cnt[e];
  if (m0 >= c) return;

  __shared__ __align__(16) bf16 As[BM][BK];   // 8 KB, linear 64B rows
  __shared__ __align__(16) bf16 Bs[BN][BK];   // 8 KB

  int l = tid & 63, w = tid >> 6;
  int rr = w * 32 + (l >> 2);        // row within tile for this lane's 16B chunk
  int cb = (l & 3) * 8;              // element offset within 32-elem row
  int ga0 = m0 + rr;      if (ga0 >= c) ga0 = c - 1;
  int ga1 = m0 + rr + 16; if (ga1 >= c) ga1 = c - 1;
  const bf16* aS0 = xb + (size_t)(elist[e * T_TOK + ga0] >> 1) * HID + cb;
  const bf16* aS1 = xb + (size_t)(elist[e * T_TOK + ga1] >> 1) * HID + cb;
  const bf16* w1te = w1t + (size_t)e * FFN * HID;
  const bf16* bS0 = w1te + (size_t)(n0 + rr) * HID + cb;
  const bf16* bS1 = w1te + (size_t)(n0 + rr + 16) * HID + cb;
  bf16* ldA0 = &As[w * 32][0];       // wave-uniform LDS bases
  bf16* ldA1 = &As[w * 32 + 16][0];
  bf16* ldB0 = &Bs[w * 32][0];
  bf16* ldB1 = &Bs[w * 32 + 16][0];

  floatx4 acc[4][4] = {};
  int fm = l & 15, quad = l >> 4, wm = (w & 1) * 64, wn = (w >> 1) * 64;

  for (int t = 0; t < HID / BK; t++) {
    __syncthreads();                 // readers done with previous tile
    GLOAD16(aS0, ldA0); GLOAD16(aS1, ldA1);
    GLOAD16(bS0, ldB0); GLOAD16(bS1, ldB1);
    aS0 += BK; aS1 += BK; bS0 += BK; bS1 += BK;
    __syncthreads();                 // compiler drains vmcnt before barrier
    bf16x8 af[4], bfr[4];
#pragma unroll
    for (int i = 0; i < 4; i++) af[i] = *(const bf16x8*)&As[wm + i * 16 + fm][quad * 8];
#pragma unroll
    for (int j = 0; j < 4; j++) bfr[j] = *(const bf16x8*)&Bs[wn + j * 16 + fm][quad * 8];
#pragma unroll
    for (int i = 0; i < 4; i++)
#pragma unroll
      for (int j = 0; j < 4; j++)
        acc[i][j] = __builtin_amdgcn_mfma_f32_16x16x32_bf16(af[i], bfr[j], acc[i][j], 0, 0, 0);
  }

  const float* b1e = b1 + (size_t)e * FFN;
#pragma unroll
  for (int i = 0; i < 4; i++) {
    int rb = m0 + wm + i * 16 + quad * 4;
#pragma unroll
    for (int j = 0; j < 4; j++) {
      int col = n0 + wn + j * 16 + fm;
      float bias = b1e[col];
#pragma unroll
      for (int r = 0; r < 4; r++) {
        int row = rb + r;
        if (row < c) {
          int slot = elist[e * T_TOK + row];
          float v = acc[i][j][r] + bias;
          float gl = 0.5f * v * (1.f + erff(v * 0.70710678118654752f));
          hbuf[(size_t)slot * FFN + col] = (bf16)gl;
        }
      }
    }
  }
}

// ---------------- GEMM2 split-K=4, fused combine: out += wt*(h @ w2 + b2?) ----------------
__global__ __launch_bounds__(256)
void gemm2_k(const bf16* __restrict__ hbuf, const bf16* __restrict__ w2t,
             const float* __restrict__ b2, const int* __restrict__ cnt,
             const int* __restrict__ elist, const float* __restrict__ ewt,
             float* __restrict__ out) {
  int e = blockIdx.z & 7;
  int ks = blockIdx.z >> 3;
  int c = cnt[e];
  int m0 = blockIdx.y * BM;
  if (m0 >= c) return;
  int n0 = blockIdx.x * BN;
  int kbeg = ks * (FFN / 4);

  __shared__ __align__(16) bf16 As[BM][BK];
  __shared__ __align__(16) bf16 Bs[BN][BK];

  int tid = threadIdx.x;
  int l = tid & 63, w = tid >> 6;
  int rr = w * 32 + (l >> 2);
  int cb = (l & 3) * 8;
  int ga0 = m0 + rr;      if (ga0 >= c) ga0 = c - 1;
  int ga1 = m0 + rr + 16; if (ga1 >= c) ga1 = c - 1;
  const bf16* aS0 = hbuf + (size_t)elist[e * T_TOK + ga0] * FFN + kbeg + cb;
  const bf16* aS1 = hbuf + (size_t)elist[e * T_TOK + ga1] * FFN + kbeg + cb;
  const bf16* w2te = w2t + (size_t)e * HID * FFN;
  const bf16* bS0 = w2te + (size_t)(n0 + rr) * FFN + kbeg + cb;
  const bf16* bS1 = w2te + (size_t)(n0 + rr + 16) * FFN + kbeg + cb;
  bf16* ldA0 = &As[w * 32][0];
  bf16* ldA1 = &As[w * 32 + 16][0];
  bf16* ldB0 = &Bs[w * 32][0];
  bf16* ldB1 = &Bs[w * 32 + 16][0];

  floatx4 acc[4][4] = {};
  int fm = l & 15, quad = l >> 4, wm = (w & 1) * 64, wn = (w >> 1) * 64;

  const int NT = (FFN / 4) / BK;
  for (int t = 0; t < NT; t++) {
    __syncthreads();
    GLOAD16(aS0, ldA0); GLOAD16(aS1, ldA1);
    GLOAD16(bS0, ldB0); GLOAD16(bS1, ldB1);
    aS0 += BK; aS1 += BK; bS0 += BK; bS1 += BK;
    __syncthreads();
    bf16x8 af[4], bfr[4];
#pragma unroll
    for (int i = 0; i < 4; i++) af[i] = *(const bf16x8*)&As[wm + i * 16 + fm][quad * 8];
#pragma unroll
    for (int j = 0; j < 4; j++) bfr[j] = *(const bf16x8*)&Bs[wn + j * 16 + fm][quad * 8];
#pragma unroll
    for (int i = 0; i < 4; i++)
#pragma unroll
      for (int j = 0; j < 4; j++)
        acc[i][j] = __builtin_amdgcn_mfma_f32_16x16x32_bf16(af[i], bfr[j], acc[i][j], 0, 0, 0);
  }

  const float* b2e = b2 + (size_t)e * HID;
#pragma unroll
  for (int i = 0; i < 4; i++) {
    int rb = m0 + wm + i * 16 + quad * 4;
#pragma unroll
    for (int j = 0; j < 4; j++) {
      int col = n0 + wn + j * 16 + fm;
      float bias = (ks == 0) ? b2e[col] : 0.f;
#pragma unroll
      for (int r = 0; r < 4; r++) {
        int row = rb + r;
        if (row < c) {
          int slot = elist[e * T_TOK + row];
          float wgt = ewt[e * T_TOK + row];
          atomicAdd(&out[(size_t)(slot >> 1) * HID + col], wgt * (acc[i][j][r] + bias));
        }
      }
    }
  }
}

extern "C" void kernel_launch(void* const* d_in, const int* in_sizes, int n_in,
                              void* d_out, int out_size, void* d_ws, size_t ws_size,
                              hipStream_t stream) {
  const float* x  = (const float*)d_in[0];
  const float* gw = (const float*)d_in[1];
  const float* gb = (const float*)d_in[2];
  const float* w1 = (const float*)d_in[3];
  const float* b1 = (const float*)d_in[4];
  const float* w2 = (const float*)d_in[5];
  const float* b2 = (const float*)d_in[6];
  float* out = (float*)d_out;

  char* ws = (char*)d_ws;
  int*   cnt   = (int*)ws;                                   // 32 B
  int*   elist = (int*)(ws + 1024);                          // 32 KB
  float* ewt   = (float*)(ws + 1024 + 32768);                // 32 KB
  bf16*  xb    = (bf16*)(ws + (1 << 16));                    // 2 MB
  bf16*  hbuf  = (bf16*)(ws + ((size_t)4 << 20));            // 16.8 MB  [4,20.8)
  bf16*  w1T   = (bf16*)(ws + ((size_t)21 << 20));           // 67.1 MB  [21,88.1)
  bool par = ws_size >= ((size_t)157 << 20);
  bf16*  w2T   = par ? (bf16*)(ws + ((size_t)89 << 20))      // 67.1 MB  [89,156.1)
                     : w1T;                                  // reuse (serial path)

  hipMemsetAsync(cnt, 0, 32, stream);
  hipMemsetAsync(out, 0, out_size, stream);
  // wconv1 (4096) | xconv (512) | router (256)
  fusedB_k<<<4864, 256, 0, stream>>>(x, xb, gw, gb, cnt, elist, ewt, w1, w1T);
  if (par) {
    // wconv2 (4096) | gemm1 (2048) overlapped in one dispatch
    gemm1f_k<<<4096 + 2048, 256, 0, stream>>>(4096, w2, w2T, xb, w1T, b1, cnt, elist, hbuf);
  } else {
    gemm1f_k<<<2048, 256, 0, stream>>>(0, w2, w2T, xb, w1T, b1, cnt, elist, hbuf);
    wconv_k<<<4096, 256, 0, stream>>>(w2, w2T, FFN, HID, 10, 7);
  }
  gemm2_k<<<dim3(HID / BN, T_TOK / BM, NEXP * 4), 256, 0, stream>>>(hbuf, w2T, b2, cnt, elist, ewt, out);
}

// Round 5
// 459.369 us; speedup vs baseline: 1.1421x; 1.1421x over previous
//
#include <hip/hip_runtime.h>

// MoE fp32: route top-2 -> gather -> bf16 MFMA GEMMs.
// v5: occupancy x MFMA-per-iter attack. Both GEMMs BM=64/BN=128/BK=64
// (~1024 live blocks = 4/CU, 16 waves/CU; 16 MFMA/iter/wave), LDS in
// [2][rows][32] split-halves (linear gload_lds chunks, bank-balanced reads).
// Weights bf16-transposed by wconv passes fused into independent launches;
// gemm blocks FIRST in the fused grid. gemm2: split-K=4 + atomic combine.

typedef __bf16 bf16;
typedef __bf16 bf16x8 __attribute__((ext_vector_type(8)));
typedef float floatx4 __attribute__((ext_vector_type(4)));

#define T_TOK 1024
#define HID 1024
#define FFN 4096
#define NEXP 8
#define BM 64
#define BN 128
#define BK 64

#define GLOAD16(g, l) __builtin_amdgcn_global_load_lds( \
    (const __attribute__((address_space(1))) void*)(g), \
    (__attribute__((address_space(3))) void*)(l), 16, 0, 0)

// ---------------- device bodies ----------------
__device__ __forceinline__ void wconv_body(const float* __restrict__ w,
                                           bf16* __restrict__ wt, int bid, int tid,
                                           int K, int N, int lgN, int lgKC) {
  int gid = bid * 256 + tid;
  int n = gid & (N - 1);
  int kc = (gid >> lgN) & ((K >> 5) - 1);
  int e = gid >> (lgN + lgKC);
  const float* src = w + ((size_t)e * K + (size_t)kc * 32) * N + n;
  bf16* dst = wt + ((size_t)e * N + n) * (size_t)K + kc * 32;
  float v[32];
#pragma unroll
  for (int j = 0; j < 32; j++) v[j] = src[(size_t)j * N];
  bf16x8 pk[4];
#pragma unroll
  for (int q = 0; q < 4; q++)
#pragma unroll
    for (int i = 0; i < 8; i++) pk[q][i] = (bf16)v[q * 8 + i];
#pragma unroll
  for (int q = 0; q < 4; q++) *(bf16x8*)(dst + q * 8) = pk[q];
}

__device__ __forceinline__ void xconv_body(const float* __restrict__ x,
                                           bf16* __restrict__ xb, int bid, int tid) {
  int i = bid * 256 + tid;
  float4 a = ((const float4*)x)[i * 2];
  float4 b = ((const float4*)x)[i * 2 + 1];
  bf16 t[8] = {(bf16)a.x, (bf16)a.y, (bf16)a.z, (bf16)a.w,
               (bf16)b.x, (bf16)b.y, (bf16)b.z, (bf16)b.w};
  *(bf16x8*)&xb[(size_t)i * 8] = *(bf16x8*)t;
}

__device__ __forceinline__ void router_body(const float* __restrict__ x,
                                            const float* __restrict__ gw,
                                            const float* __restrict__ gb,
                                            int* __restrict__ cnt, int* __restrict__ elist,
                                            float* __restrict__ ewt, int bid, int tid) {
  int wave = tid >> 6;
  int lane = tid & 63;
  int t = bid * 4 + wave;
  const float* xr = x + (size_t)t * HID;
  float xv[16];
#pragma unroll
  for (int j = 0; j < 16; j++) xv[j] = xr[lane + 64 * j];
  float logits[NEXP];
#pragma unroll
  for (int e = 0; e < NEXP; e++) {
    const float* g = gw + (size_t)e * HID;
    float s = 0.f;
#pragma unroll
    for (int j = 0; j < 16; j++) s += xv[j] * g[lane + 64 * j];
#pragma unroll
    for (int off = 32; off; off >>= 1) s += __shfl_xor(s, off, 64);
    logits[e] = s + gb[e];
  }
  int i0 = 0; float l0 = logits[0];
#pragma unroll
  for (int e = 1; e < NEXP; e++) if (logits[e] > l0) { l0 = logits[e]; i0 = e; }
  int i1 = -1; float l1 = -3.0e38f;
#pragma unroll
  for (int e = 0; e < NEXP; e++) if (e != i0 && logits[e] > l1) { l1 = logits[e]; i1 = e; }
  if (lane == 0) {
    float w0 = 1.f / (1.f + expf(l1 - l0));
    float w1 = 1.f - w0;
    int p0 = atomicAdd(cnt + i0, 1);
    elist[i0 * T_TOK + p0] = t * 2 + 0; ewt[i0 * T_TOK + p0] = w0;
    int p1 = atomicAdd(cnt + i1, 1);
    elist[i1 * T_TOK + p1] = t * 2 + 1; ewt[i1 * T_TOK + p1] = w1;
  }
}

// ---------------- Launch B: wconv1 | xconv | router (all independent) ----------------
__global__ __launch_bounds__(256)
void fusedB_k(const float* __restrict__ x, bf16* __restrict__ xb,
              const float* __restrict__ gw, const float* __restrict__ gb,
              int* __restrict__ cnt, int* __restrict__ elist, float* __restrict__ ewt,
              const float* __restrict__ w1, bf16* __restrict__ w1t) {
  int bid = blockIdx.x;
  int tid = threadIdx.x;
  if (bid < 4096) { wconv_body(w1, w1t, bid, tid, HID, FFN, 12, 5); return; }
  bid -= 4096;
  if (bid < 512) { xconv_body(x, xb, bid, tid); return; }
  router_body(x, gw, gb, cnt, elist, ewt, bid - 512, tid);
}

__global__ __launch_bounds__(256)
void wconv_k(const float* __restrict__ w, bf16* __restrict__ wt,
             int K, int N, int lgN, int lgKC) {
  wconv_body(w, wt, blockIdx.x, threadIdx.x, K, N, lgN, lgKC);
}

// ---------------- Launch C: gemm1 (h = gelu(Xg @ w1 + b1)) | wconv2 ----------------
// gemm blocks FIRST so they grab CUs immediately; wconv2 backfills.
__global__ __launch_bounds__(256)
void gemm1f_k(int ngemm, const float* __restrict__ w2, bf16* __restrict__ w2t,
              const bf16* __restrict__ xb, const bf16* __restrict__ w1t,
              const float* __restrict__ b1, const int* __restrict__ cnt,
              const int* __restrict__ elist, bf16* __restrict__ hbuf) {
  int tid = threadIdx.x;
  int bid = blockIdx.x;
  if (bid >= ngemm) { wconv_body(w2, w2t, bid - ngemm, tid, FFN, HID, 10, 7); return; }
  int e = bid >> 9;                    // 8 e x 16 m x 32 n
  int m0 = ((bid >> 5) & 15) * BM;
  int n0 = (bid & 31) * BN;
  int c = cnt[e];
  if (m0 >= c) return;

  __shared__ __align__(16) bf16 As[2][BM][32];   // 8 KB  (kk split-halves)
  __shared__ __align__(16) bf16 Bs[2][BN][32];   // 16 KB

  int l = tid & 63, w = tid >> 6;
  int l4 = l >> 2;                     // row within 16-row chunk
  int k8 = (l & 3) * 8;                // element offset within 32
  // A: wave w stages rows w*16..+15, both kk halves (1 row ptr, 2 GLOAD16)
  int gra = m0 + w * 16 + l4; if (gra >= c) gra = c - 1;
  const bf16* ap = xb + (size_t)(elist[e * T_TOK + gra] >> 1) * HID + k8;
  // B: wave w stages n-rows (2w)*16..+15 and (2w+1)*16..+15 (2 ptrs, 4 GLOAD16)
  const bf16* w1te = w1t + (size_t)e * FFN * HID;
  const bf16* bp0 = w1te + (size_t)(n0 + (2 * w) * 16 + l4) * HID + k8;
  const bf16* bp1 = w1te + (size_t)(n0 + (2 * w + 1) * 16 + l4) * HID + k8;
  bf16* ldA0 = &As[0][w * 16][0];
  bf16* ldA1 = &As[1][w * 16][0];
  bf16* ldB00 = &Bs[0][(2 * w) * 16][0];
  bf16* ldB01 = &Bs[1][(2 * w) * 16][0];
  bf16* ldB10 = &Bs[0][(2 * w + 1) * 16][0];
  bf16* ldB11 = &Bs[1][(2 * w + 1) * 16][0];

  floatx4 acc[4][2] = {};
  int fm = l & 15, quad = l >> 4;
  int wn = w * 32;

  for (int t = 0; t < HID / BK; t++) {
    __syncthreads();                   // readers done with previous tile
    GLOAD16(ap, ldA0);       GLOAD16(ap + 32, ldA1);
    GLOAD16(bp0, ldB00);     GLOAD16(bp0 + 32, ldB01);
    GLOAD16(bp1, ldB10);     GLOAD16(bp1 + 32, ldB11);
    ap += BK; bp0 += BK; bp1 += BK;
    __syncthreads();                   // vmcnt drained before barrier
    bf16x8 af[2][4], bfr[2][2];
#pragma unroll
    for (int kk = 0; kk < 2; kk++) {
#pragma unroll
      for (int i = 0; i < 4; i++) af[kk][i] = *(const bf16x8*)&As[kk][i * 16 + fm][quad * 8];
#pragma unroll
      for (int j = 0; j < 2; j++) bfr[kk][j] = *(const bf16x8*)&Bs[kk][wn + j * 16 + fm][quad * 8];
    }
#pragma unroll
    for (int kk = 0; kk < 2; kk++)
#pragma unroll
      for (int i = 0; i < 4; i++)
#pragma unroll
        for (int j = 0; j < 2; j++)
          acc[i][j] = __builtin_amdgcn_mfma_f32_16x16x32_bf16(af[kk][i], bfr[kk][j], acc[i][j], 0, 0, 0);
  }

  const float* b1e = b1 + (size_t)e * FFN;
#pragma unroll
  for (int i = 0; i < 4; i++) {
    int rb = m0 + i * 16 + quad * 4;
#pragma unroll
    for (int j = 0; j < 2; j++) {
      int col = n0 + wn + j * 16 + fm;
      float bias = b1e[col];
#pragma unroll
      for (int r = 0; r < 4; r++) {
        int row = rb + r;
        if (row < c) {
          int slot = elist[e * T_TOK + row];
          float v = acc[i][j][r] + bias;
          float gl = 0.5f * v * (1.f + erff(v * 0.70710678118654752f));
          hbuf[(size_t)slot * FFN + col] = (bf16)gl;
        }
      }
    }
  }
}

// ---------------- GEMM2 split-K=4, fused combine: out += wt*(h @ w2 + b2?) ----------------
__global__ __launch_bounds__(256)
void gemm2_k(const bf16* __restrict__ hbuf, const bf16* __restrict__ w2t,
             const float* __restrict__ b2, const int* __restrict__ cnt,
             const int* __restrict__ elist, const float* __restrict__ ewt,
             float* __restrict__ out) {
  int e = blockIdx.z & 7;
  int ks = blockIdx.z >> 3;
  int c = cnt[e];
  int m0 = blockIdx.y * BM;
  if (m0 >= c) return;
  int n0 = blockIdx.x * BN;
  int kbeg = ks * (FFN / 4);

  __shared__ __align__(16) bf16 As[2][BM][32];
  __shared__ __align__(16) bf16 Bs[2][BN][32];

  int tid = threadIdx.x;
  int l = tid & 63, w = tid >> 6;
  int l4 = l >> 2;
  int k8 = (l & 3) * 8;
  int gra = m0 + w * 16 + l4; if (gra >= c) gra = c - 1;
  const bf16* ap = hbuf + (size_t)elist[e * T_TOK + gra] * FFN + kbeg + k8;
  const bf16* w2te = w2t + (size_t)e * HID * FFN;
  const bf16* bp0 = w2te + (size_t)(n0 + (2 * w) * 16 + l4) * FFN + kbeg + k8;
  const bf16* bp1 = w2te + (size_t)(n0 + (2 * w + 1) * 16 + l4) * FFN + kbeg + k8;
  bf16* ldA0 = &As[0][w * 16][0];
  bf16* ldA1 = &As[1][w * 16][0];
  bf16* ldB00 = &Bs[0][(2 * w) * 16][0];
  bf16* ldB01 = &Bs[1][(2 * w) * 16][0];
  bf16* ldB10 = &Bs[0][(2 * w + 1) * 16][0];
  bf16* ldB11 = &Bs[1][(2 * w + 1) * 16][0];

  floatx4 acc[4][2] = {};
  int fm = l & 15, quad = l >> 4;
  int wn = w * 32;

  const int NT = (FFN / 4) / BK;
  for (int t = 0; t < NT; t++) {
    __syncthreads();
    GLOAD16(ap, ldA0);       GLOAD16(ap + 32, ldA1);
    GLOAD16(bp0, ldB00);     GLOAD16(bp0 + 32, ldB01);
    GLOAD16(bp1, ldB10);     GLOAD16(bp1 + 32, ldB11);
    ap += BK; bp0 += BK; bp1 += BK;
    __syncthreads();
    bf16x8 af[2][4], bfr[2][2];
#pragma unroll
    for (int kk = 0; kk < 2; kk++) {
#pragma unroll
      for (int i = 0; i < 4; i++) af[kk][i] = *(const bf16x8*)&As[kk][i * 16 + fm][quad * 8];
#pragma unroll
      for (int j = 0; j < 2; j++) bfr[kk][j] = *(const bf16x8*)&Bs[kk][wn + j * 16 + fm][quad * 8];
    }
#pragma unroll
    for (int kk = 0; kk < 2; kk++)
#pragma unroll
      for (int i = 0; i < 4; i++)
#pragma unroll
        for (int j = 0; j < 2; j++)
          acc[i][j] = __builtin_amdgcn_mfma_f32_16x16x32_bf16(af[kk][i], bfr[kk][j], acc[i][j], 0, 0, 0);
  }

  const float* b2e = b2 + (size_t)e * HID;
#pragma unroll
  for (int i = 0; i < 4; i++) {
    int rb = m0 + i * 16 + quad * 4;
#pragma unroll
    for (int j = 0; j < 2; j++) {
      int col = n0 + wn + j * 16 + fm;
      float bias = (ks == 0) ? b2e[col] : 0.f;
#pragma unroll
      for (int r = 0; r < 4; r++) {
        int row = rb + r;
        if (row < c) {
          int slot = elist[e * T_TOK + row];
          float wgt = ewt[e * T_TOK + row];
          atomicAdd(&out[(size_t)(slot >> 1) * HID + col], wgt * (acc[i][j][r] + bias));
        }
      }
    }
  }
}

extern "C" void kernel_launch(void* const* d_in, const int* in_sizes, int n_in,
                              void* d_out, int out_size, void* d_ws, size_t ws_size,
                              hipStream_t stream) {
  const float* x  = (const float*)d_in[0];
  const float* gw = (const float*)d_in[1];
  const float* gb = (const float*)d_in[2];
  const float* w1 = (const float*)d_in[3];
  const float* b1 = (const float*)d_in[4];
  const float* w2 = (const float*)d_in[5];
  const float* b2 = (const float*)d_in[6];
  float* out = (float*)d_out;

  char* ws = (char*)d_ws;
  int*   cnt   = (int*)ws;                                   // 32 B
  int*   elist = (int*)(ws + 1024);                          // 32 KB
  float* ewt   = (float*)(ws + 1024 + 32768);                // 32 KB
  bf16*  xb    = (bf16*)(ws + (1 << 16));                    // 2 MB
  bf16*  hbuf  = (bf16*)(ws + ((size_t)4 << 20));            // 16.8 MB  [4,20.8)
  bf16*  w1T   = (bf16*)(ws + ((size_t)21 << 20));           // 67.1 MB  [21,88.1)
  bool par = ws_size >= ((size_t)157 << 20);
  bf16*  w2T   = par ? (bf16*)(ws + ((size_t)89 << 20))      // 67.1 MB  [89,156.1)
                     : w1T;                                  // reuse (serial path)

  hipMemsetAsync(cnt, 0, 32, stream);
  hipMemsetAsync(out, 0, out_size, stream);
  // wconv1 (4096) | xconv (512) | router (256)
  fusedB_k<<<4864, 256, 0, stream>>>(x, xb, gw, gb, cnt, elist, ewt, w1, w1T);
  if (par) {
    // gemm1 (4096, first) | wconv2 (4096) overlapped in one dispatch
    gemm1f_k<<<8192, 256, 0, stream>>>(4096, w2, w2T, xb, w1T, b1, cnt, elist, hbuf);
  } else {
    gemm1f_k<<<4096, 256, 0, stream>>>(4096, w2, w2T, xb, w1T, b1, cnt, elist, hbuf);
    wconv_k<<<4096, 256, 0, stream>>>(w2, w2T, FFN, HID, 10, 7);
  }
  gemm2_k<<<dim3(HID / BN, T_TOK / BM, NEXP * 4), 256, 0, stream>>>(hbuf, w2T, b2, cnt, elist, ewt, out);
}